// Round 1
// baseline (262.726 us; speedup 1.0000x reference)
//
#include <hip/hip_runtime.h>
#include <cmath>

#define B_ 4
#define N_ 512
#define F_ 128
#define BN_ (B_*N_)   // 2048

__device__ __forceinline__ float elu_f(float x) {
    return x > 0.f ? x : __expf(x) - 1.f;
}

// ---------------------------------------------------------------------------
// Kernel A: Hi = H @ dW1[:F] + db1 (bias pre-folded), Hj = H @ dW1[F:]
// grid BN/8 = 256 blocks, 128 threads. 8 rows per block staged in LDS.
// ---------------------------------------------------------------------------
__global__ __launch_bounds__(128) void k_lin1(
    const float* __restrict__ H, const float* __restrict__ dW1,
    const float* __restrict__ db1,
    float* __restrict__ Hi, float* __restrict__ Hj) {
    __shared__ float sH[8][F_];
    const int t = threadIdx.x;
    const int row0 = blockIdx.x * 8;
    #pragma unroll
    for (int r = 0; r < 8; ++r) sH[r][t] = H[(row0 + r) * F_ + t];
    __syncthreads();
    float accA[8], accB[8];
    #pragma unroll
    for (int r = 0; r < 8; ++r) { accA[r] = 0.f; accB[r] = 0.f; }
    for (int k = 0; k < F_; ++k) {
        const float wa = dW1[k * F_ + t];
        const float wb = dW1[(F_ + k) * F_ + t];
        #pragma unroll
        for (int r = 0; r < 8; ++r) {
            accA[r] = fmaf(sH[r][k], wa, accA[r]);
            accB[r] = fmaf(sH[r][k], wb, accB[r]);
        }
    }
    const float bias = db1[t];
    #pragma unroll
    for (int r = 0; r < 8; ++r) {
        Hi[(row0 + r) * F_ + t] = accA[r] + bias;  // db1 folded in
        Hj[(row0 + r) * F_ + t] = accB[r];
    }
}

// ---------------------------------------------------------------------------
// Kernel B: per row i: max over connected j of logit(i,j); sigmoid once.
// Also deg (count A>0) and the bool mask output.
// grid BN/4 = 512 blocks, 256 threads. Each WAVE owns one i (scalar Hi/dW2
// loads via readfirstlane); each lane owns 8 j's (independent acc chains).
// ---------------------------------------------------------------------------
__global__ __launch_bounds__(256) void k_score(
    const float* __restrict__ Hi, const float* __restrict__ Hj,
    const float* __restrict__ A, const float* __restrict__ dW2,
    const float* __restrict__ db2,
    float* __restrict__ maxc, float* __restrict__ degv,
    float* __restrict__ maskout) {
    const int t = threadIdx.x;
    const int lane = t & 63;
    const int w = __builtin_amdgcn_readfirstlane(t >> 6);  // wave id, SGPR
    const int bi = blockIdx.x * 4 + w;                     // flat row (b*N+i)
    const int b = bi >> 9;

    const float* hi_row  = Hi + (size_t)bi * F_;           // wave-uniform
    const float* hj_base = Hj + (size_t)b * N_ * F_;
    const float* a_row   = A + (size_t)bi * N_;

    const float* hj_row[8];
    #pragma unroll
    for (int r = 0; r < 8; ++r) hj_row[r] = hj_base + (size_t)(lane + 64 * r) * F_;

    float acc[8];
    #pragma unroll
    for (int r = 0; r < 8; ++r) acc[r] = 0.f;

    #pragma unroll 2
    for (int f = 0; f < F_; f += 4) {
        const float4 hi4 = *reinterpret_cast<const float4*>(hi_row + f);
        const float4 w24 = *reinterpret_cast<const float4*>(dW2 + f);
        #pragma unroll
        for (int r = 0; r < 8; ++r) {
            const float4 hj4 = *reinterpret_cast<const float4*>(hj_row[r] + f);
            acc[r] = fmaf(elu_f(hi4.x + hj4.x), w24.x, acc[r]);
            acc[r] = fmaf(elu_f(hi4.y + hj4.y), w24.y, acc[r]);
            acc[r] = fmaf(elu_f(hi4.z + hj4.z), w24.z, acc[r]);
            acc[r] = fmaf(elu_f(hi4.w + hj4.w), w24.w, acc[r]);
        }
    }

    float mx = -INFINITY;
    int cnt = 0;
    #pragma unroll
    for (int r = 0; r < 8; ++r) {
        const float a = a_row[lane + 64 * r];
        if (a > 0.f)  cnt++;
        if (a > 0.1f) mx = fmaxf(mx, acc[r]);
    }
    // wave-level reduce (64 lanes)
    #pragma unroll
    for (int off = 1; off < 64; off <<= 1) {
        mx = fmaxf(mx, __shfl_xor(mx, off));
        cnt += __shfl_xor(cnt, off);
    }
    if (lane == 0) {
        const float mc = (mx > -INFINITY)
                       ? 1.f / (1.f + __expf(-(mx + db2[0]))) : 0.f;
        maxc[bi] = mc;
        degv[bi] = (float)cnt;
        maskout[bi] = (mc > 0.5f) ? 1.f : 0.f;  // bool output as 0/1 float
    }
}

// ---------------------------------------------------------------------------
// Kernel N: neighbor_feat[bi][f] = sum_{j: A>0} H[b][j][f] / max(deg,1)
// grid BN = 2048 blocks, 128 threads (thread = f). A row read is uniform
// per iteration -> scalar loads; H reads coalesced 512B.
// ---------------------------------------------------------------------------
__global__ __launch_bounds__(128) void k_nbr(
    const float* __restrict__ A, const float* __restrict__ H,
    const float* __restrict__ degv, float* __restrict__ nf) {
    const int f = threadIdx.x;
    const int bi = blockIdx.x;
    const int b = bi >> 9;
    const float* a_row  = A + (size_t)bi * N_;
    const float* h_base = H + (size_t)b * N_ * F_;
    float s = 0.f;
    #pragma unroll 4
    for (int j = 0; j < N_; ++j) {
        if (a_row[j] > 0.f) s += h_base[j * F_ + f];
    }
    const float d = degv[bi];
    nf[bi * F_ + f] = s / fmaxf(d, 1.f);
}

// ---------------------------------------------------------------------------
// Kernel C: res = elu([H,nf,maxc] @ rW1 + rb1) @ rW2 + rb2; select per row.
// grid BN/8 = 256 blocks, 128 threads, 8 rows per block.
// ---------------------------------------------------------------------------
__global__ __launch_bounds__(128) void k_mlp(
    const float* __restrict__ H, const float* __restrict__ nf,
    const float* __restrict__ maxc, const float* __restrict__ degv,
    const float* __restrict__ rW1, const float* __restrict__ rb1,
    const float* __restrict__ rW2, const float* __restrict__ rb2,
    float* __restrict__ out) {
    __shared__ float sC[8][2 * F_ + 1];
    __shared__ float sL1[8][F_];
    const int t = threadIdx.x;
    const int row0 = blockIdx.x * 8;
    #pragma unroll
    for (int r = 0; r < 8; ++r) {
        sC[r][t]      = H [(row0 + r) * F_ + t];
        sC[r][F_ + t] = nf[(row0 + r) * F_ + t];
        if (t == 0) sC[r][2 * F_] = maxc[row0 + r];
    }
    __syncthreads();
    float acc[8];
    #pragma unroll
    for (int r = 0; r < 8; ++r) acc[r] = rb1[t];
    for (int k = 0; k < 2 * F_ + 1; ++k) {
        const float wv = rW1[k * F_ + t];
        #pragma unroll
        for (int r = 0; r < 8; ++r) acc[r] = fmaf(sC[r][k], wv, acc[r]);
    }
    #pragma unroll
    for (int r = 0; r < 8; ++r) sL1[r][t] = elu_f(acc[r]);
    __syncthreads();
    float acc2[8];
    #pragma unroll
    for (int r = 0; r < 8; ++r) acc2[r] = rb2[t];
    for (int k = 0; k < F_; ++k) {
        const float wv = rW2[k * F_ + t];
        #pragma unroll
        for (int r = 0; r < 8; ++r) acc2[r] = fmaf(sL1[r][k], wv, acc2[r]);
    }
    #pragma unroll
    for (int r = 0; r < 8; ++r) {
        const int row = row0 + r;
        const bool upd = (maxc[row] > 0.5f) && (degv[row] > 0.f);
        out[row * F_ + t] = upd ? acc2[r] : sC[r][t];
    }
}

// ---------------------------------------------------------------------------
extern "C" void kernel_launch(void* const* d_in, const int* in_sizes, int n_in,
                              void* d_out, int out_size, void* d_ws, size_t ws_size,
                              hipStream_t stream) {
    const float* H   = (const float*)d_in[0];
    const float* A   = (const float*)d_in[1];
    const float* dW1 = (const float*)d_in[2];
    const float* db1 = (const float*)d_in[3];
    const float* dW2 = (const float*)d_in[4];
    const float* db2 = (const float*)d_in[5];
    const float* rW1 = (const float*)d_in[6];
    const float* rb1 = (const float*)d_in[7];
    const float* rW2 = (const float*)d_in[8];
    const float* rb2 = (const float*)d_in[9];

    float* ws   = (float*)d_ws;
    float* Hi   = ws;                      // [BN][F]
    float* Hj   = Hi + BN_ * F_;           // [BN][F]
    float* maxc = Hj + BN_ * F_;           // [BN]
    float* degv = maxc + BN_;              // [BN]
    float* nf   = degv + BN_;              // [BN][F]

    float* out      = (float*)d_out;       // [BN][F] H_resolved
    float* mask_out = out + BN_ * F_;      // [BN] contra_mask as 0/1

    k_lin1 <<<BN_ / 8, 128, 0, stream>>>(H, dW1, db1, Hi, Hj);
    k_score<<<BN_ / 4, 256, 0, stream>>>(Hi, Hj, A, dW2, db2, maxc, degv, mask_out);
    k_nbr  <<<BN_,     128, 0, stream>>>(A, H, degv, nf);
    k_mlp  <<<BN_ / 8, 128, 0, stream>>>(H, nf, maxc, degv, rW1, rb1, rW2, rb2, out);
}

// Round 2
// 82.194 us; speedup vs baseline: 3.1964x; 3.1964x over previous
//
#include <hip/hip_runtime.h>
#include <cmath>

#define B_ 4
#define N_ 512
#define F_ 128
#define BN_ (B_*N_)   // 2048

__device__ __forceinline__ float elu_f(float x) {
    return x > 0.f ? x : __expf(x) - 1.f;
}
__device__ __forceinline__ float rfl(float x) {  // force wave-uniform -> SGPR
    return __uint_as_float(__builtin_amdgcn_readfirstlane(__float_as_uint(x)));
}

// ---------------------------------------------------------------------------
// Kernel A: Hi = H @ dW1[:F] + db1 (bias folded), HjT[b][f][n] = (H @ dW1[F:])^T
// grid BN/8 = 256 blocks, 128 threads. 8 rows per block staged in LDS.
// ---------------------------------------------------------------------------
__global__ __launch_bounds__(128) void k_lin1(
    const float* __restrict__ H, const float* __restrict__ dW1,
    const float* __restrict__ db1,
    float* __restrict__ Hi, float* __restrict__ HjT) {
    __shared__ float sH[8][F_];
    const int t = threadIdx.x;
    const int row0 = blockIdx.x * 8;
    #pragma unroll
    for (int r = 0; r < 8; ++r) sH[r][t] = H[(row0 + r) * F_ + t];
    __syncthreads();
    float accA[8], accB[8];
    #pragma unroll
    for (int r = 0; r < 8; ++r) { accA[r] = 0.f; accB[r] = 0.f; }
    for (int k = 0; k < F_; ++k) {
        const float wa = dW1[k * F_ + t];
        const float wb = dW1[(F_ + k) * F_ + t];
        #pragma unroll
        for (int r = 0; r < 8; ++r) {
            accA[r] = fmaf(sH[r][k], wa, accA[r]);
            accB[r] = fmaf(sH[r][k], wb, accB[r]);
        }
    }
    const float bias = db1[t];
    const int b  = row0 >> 9;
    const int n0 = row0 & 511;
    float* hjt = HjT + ((size_t)b * F_ + t) * N_ + n0;
    #pragma unroll
    for (int r = 0; r < 8; ++r) {
        Hi[(row0 + r) * F_ + t] = accA[r] + bias;  // db1 folded in
        hjt[r] = accB[r];                          // transposed store
    }
}

// ---------------------------------------------------------------------------
// Kernel B: per row i: max over connected j of logit(i,j); sigmoid once.
// Wave owns one i; lane owns 8 j's. HjT layout -> coalesced 256B reads.
// grid BN/4 = 512 blocks, 256 threads.
// ---------------------------------------------------------------------------
__global__ __launch_bounds__(256) void k_score(
    const float* __restrict__ Hi, const float* __restrict__ HjT,
    const float* __restrict__ A, const float* __restrict__ dW2,
    const float* __restrict__ db2,
    float* __restrict__ maxc, float* __restrict__ degv,
    float* __restrict__ maskout) {
    const int t = threadIdx.x;
    const int lane = t & 63;
    const int w = __builtin_amdgcn_readfirstlane(t >> 6);
    const int bi = blockIdx.x * 4 + w;                     // flat row (b*N+i)
    const int b = bi >> 9;

    const float* hi_row = Hi + (size_t)bi * F_;            // wave-uniform
    const float* hjT    = HjT + (size_t)b * F_ * N_ + lane;
    const float* a_row  = A + (size_t)bi * N_;

    float acc[8];
    #pragma unroll
    for (int r = 0; r < 8; ++r) acc[r] = 0.f;

    #pragma unroll 4
    for (int f = 0; f < F_; ++f) {
        const float hi = rfl(hi_row[f]);
        const float wv = rfl(dW2[f]);
        const float* hrow = hjT + (size_t)f * N_;
        #pragma unroll
        for (int r = 0; r < 8; ++r) {
            acc[r] = fmaf(elu_f(hi + hrow[r * 64]), wv, acc[r]);
        }
    }

    float mx = -INFINITY;
    int cnt = 0;
    #pragma unroll
    for (int r = 0; r < 8; ++r) {
        const float a = a_row[lane + 64 * r];
        if (a > 0.f)  cnt++;
        if (a > 0.1f) mx = fmaxf(mx, acc[r]);
    }
    #pragma unroll
    for (int off = 1; off < 64; off <<= 1) {
        mx = fmaxf(mx, __shfl_xor(mx, off));
        cnt += __shfl_xor(cnt, off);
    }
    if (lane == 0) {
        const float mc = (mx > -INFINITY)
                       ? 1.f / (1.f + __expf(-(mx + db2[0]))) : 0.f;
        maxc[bi] = mc;
        degv[bi] = (float)cnt;
        maskout[bi] = (mc > 0.5f) ? 1.f : 0.f;
    }
}

// ---------------------------------------------------------------------------
// Kernel N: neighbor_feat[bi][f] = sum_{j: A>0} H[b][j][f] / max(deg,1)
// Branchless: 0/1 mask staged in LDS, unconditional fmaf -> deep pipelining.
// 2 rows per block, 256 threads: f = t&127, j-half = t>>7.
// ---------------------------------------------------------------------------
__global__ __launch_bounds__(256) void k_nbr(
    const float* __restrict__ A, const float* __restrict__ H,
    const float* __restrict__ degv, float* __restrict__ nf) {
    __shared__ float sm[2][N_];
    __shared__ float part[2][F_];
    const int t  = threadIdx.x;
    const int f  = t & 127;
    const int jh = t >> 7;                 // 0 or 1 (j-half)
    const int bi0 = blockIdx.x * 2;
    const int b = bi0 >> 9;

    #pragma unroll
    for (int r = 0; r < 2; ++r)
        for (int j = t; j < N_; j += 256)
            sm[r][j] = (A[(size_t)(bi0 + r) * N_ + j] > 0.f) ? 1.f : 0.f;
    __syncthreads();

    const float* hb = H + ((size_t)b * N_ + jh * 256) * F_ + f;
    const float* m0 = &sm[0][jh * 256];
    const float* m1 = &sm[1][jh * 256];
    float a0 = 0.f, a1 = 0.f;
    #pragma unroll 8
    for (int j = 0; j < 256; ++j) {
        const float h = hb[(size_t)j * F_];
        a0 = fmaf(m0[j], h, a0);
        a1 = fmaf(m1[j], h, a1);
    }
    if (jh == 1) { part[0][f] = a0; part[1][f] = a1; }
    __syncthreads();
    if (jh == 0) {
        const float s0 = a0 + part[0][f];
        const float s1 = a1 + part[1][f];
        nf[(size_t)(bi0 + 0) * F_ + f] = s0 / fmaxf(degv[bi0 + 0], 1.f);
        nf[(size_t)(bi0 + 1) * F_ + f] = s1 / fmaxf(degv[bi0 + 1], 1.f);
    }
}

// ---------------------------------------------------------------------------
// Kernel C: res = elu([H,nf,maxc] @ rW1 + rb1) @ rW2 + rb2; select per row.
// grid BN/8 = 256 blocks, 128 threads, 8 rows per block. b128 LDS reads.
// ---------------------------------------------------------------------------
__global__ __launch_bounds__(128) void k_mlp(
    const float* __restrict__ H, const float* __restrict__ nf,
    const float* __restrict__ maxc, const float* __restrict__ degv,
    const float* __restrict__ rW1, const float* __restrict__ rb1,
    const float* __restrict__ rW2, const float* __restrict__ rb2,
    float* __restrict__ out) {
    __shared__ float sC[8][260];           // 257 used, padded to 16B multiple
    __shared__ float sL1[8][F_];
    const int t = threadIdx.x;
    const int row0 = blockIdx.x * 8;
    #pragma unroll
    for (int r = 0; r < 8; ++r) {
        sC[r][t]      = H [(row0 + r) * F_ + t];
        sC[r][F_ + t] = nf[(row0 + r) * F_ + t];
        if (t == 0) sC[r][2 * F_] = maxc[row0 + r];
    }
    __syncthreads();
    float acc[8];
    #pragma unroll
    for (int r = 0; r < 8; ++r) acc[r] = rb1[t];
    for (int k4 = 0; k4 < 64; ++k4) {
        const int k = k4 * 4;
        const float w0 = rW1[(k + 0) * F_ + t];
        const float w1 = rW1[(k + 1) * F_ + t];
        const float w2 = rW1[(k + 2) * F_ + t];
        const float w3 = rW1[(k + 3) * F_ + t];
        #pragma unroll
        for (int r = 0; r < 8; ++r) {
            const float4 c = *reinterpret_cast<const float4*>(&sC[r][k]);
            acc[r] = fmaf(c.x, w0, acc[r]);
            acc[r] = fmaf(c.y, w1, acc[r]);
            acc[r] = fmaf(c.z, w2, acc[r]);
            acc[r] = fmaf(c.w, w3, acc[r]);
        }
    }
    {
        const float w256 = rW1[256 * F_ + t];
        #pragma unroll
        for (int r = 0; r < 8; ++r) acc[r] = fmaf(sC[r][256], w256, acc[r]);
    }
    #pragma unroll
    for (int r = 0; r < 8; ++r) sL1[r][t] = elu_f(acc[r]);
    __syncthreads();
    float acc2[8];
    #pragma unroll
    for (int r = 0; r < 8; ++r) acc2[r] = rb2[t];
    for (int k4 = 0; k4 < 32; ++k4) {
        const int k = k4 * 4;
        const float w0 = rW2[(k + 0) * F_ + t];
        const float w1 = rW2[(k + 1) * F_ + t];
        const float w2 = rW2[(k + 2) * F_ + t];
        const float w3 = rW2[(k + 3) * F_ + t];
        #pragma unroll
        for (int r = 0; r < 8; ++r) {
            const float4 c = *reinterpret_cast<const float4*>(&sL1[r][k]);
            acc2[r] = fmaf(c.x, w0, acc2[r]);
            acc2[r] = fmaf(c.y, w1, acc2[r]);
            acc2[r] = fmaf(c.z, w2, acc2[r]);
            acc2[r] = fmaf(c.w, w3, acc2[r]);
        }
    }
    #pragma unroll
    for (int r = 0; r < 8; ++r) {
        const int row = row0 + r;
        const bool upd = (maxc[row] > 0.5f) && (degv[row] > 0.f);
        out[row * F_ + t] = upd ? acc2[r] : sC[r][t];
    }
}

// ---------------------------------------------------------------------------
extern "C" void kernel_launch(void* const* d_in, const int* in_sizes, int n_in,
                              void* d_out, int out_size, void* d_ws, size_t ws_size,
                              hipStream_t stream) {
    const float* H   = (const float*)d_in[0];
    const float* A   = (const float*)d_in[1];
    const float* dW1 = (const float*)d_in[2];
    const float* db1 = (const float*)d_in[3];
    const float* dW2 = (const float*)d_in[4];
    const float* db2 = (const float*)d_in[5];
    const float* rW1 = (const float*)d_in[6];
    const float* rb1 = (const float*)d_in[7];
    const float* rW2 = (const float*)d_in[8];
    const float* rb2 = (const float*)d_in[9];

    float* ws   = (float*)d_ws;
    float* Hi   = ws;                      // [BN][F]
    float* HjT  = Hi + BN_ * F_;           // [B][F][N]
    float* maxc = HjT + BN_ * F_;          // [BN]
    float* degv = maxc + BN_;              // [BN]
    float* nf   = degv + BN_;              // [BN][F]

    float* out      = (float*)d_out;       // [BN][F] H_resolved
    float* mask_out = out + BN_ * F_;      // [BN] contra_mask as 0/1

    k_lin1 <<<BN_ / 8, 128, 0, stream>>>(H, dW1, db1, Hi, HjT);
    k_score<<<BN_ / 4, 256, 0, stream>>>(Hi, HjT, A, dW2, db2, maxc, degv, mask_out);
    k_nbr  <<<BN_ / 2, 256, 0, stream>>>(A, H, degv, nf);
    k_mlp  <<<BN_ / 8, 128, 0, stream>>>(H, nf, maxc, degv, rW1, rb1, rW2, rb2, out);
}

// Round 3
// 71.230 us; speedup vs baseline: 3.6884x; 1.1539x over previous
//
#include <hip/hip_runtime.h>
#include <cmath>

#define B_ 4
#define N_ 512
#define F_ 128
#define BN_ (B_*N_)   // 2048

__device__ __forceinline__ float elu_f(float x) {
    return x > 0.f ? x : __expf(x) - 1.f;
}

// ---------------------------------------------------------------------------
// Kernel A: Hi = H @ dW1[:F] + db1 (bias folded), HjT[b][f][n] = (H @ dW1[F:])^T
// grid BN/8 = 256 blocks, 128 threads. 8 rows per block staged in LDS.
// ---------------------------------------------------------------------------
__global__ __launch_bounds__(128) void k_lin1(
    const float* __restrict__ H, const float* __restrict__ dW1,
    const float* __restrict__ db1,
    float* __restrict__ Hi, float* __restrict__ HjT) {
    __shared__ float sH[8][F_];
    const int t = threadIdx.x;
    const int row0 = blockIdx.x * 8;
    #pragma unroll
    for (int r = 0; r < 8; ++r) sH[r][t] = H[(row0 + r) * F_ + t];
    __syncthreads();
    float accA[8], accB[8];
    #pragma unroll
    for (int r = 0; r < 8; ++r) { accA[r] = 0.f; accB[r] = 0.f; }
    for (int k = 0; k < F_; ++k) {
        const float wa = dW1[k * F_ + t];
        const float wb = dW1[(F_ + k) * F_ + t];
        #pragma unroll
        for (int r = 0; r < 8; ++r) {
            accA[r] = fmaf(sH[r][k], wa, accA[r]);
            accB[r] = fmaf(sH[r][k], wb, accB[r]);
        }
    }
    const float bias = db1[t];
    const int b  = row0 >> 9;
    const int n0 = row0 & 511;
    float* hjt = HjT + ((size_t)b * F_ + t) * N_ + n0;
    #pragma unroll
    for (int r = 0; r < 8; ++r) {
        Hi[(row0 + r) * F_ + t] = accA[r] + bias;  // db1 folded in
        hjt[r] = accB[r];                          // transposed store
    }
}

// ---------------------------------------------------------------------------
// Kernel B: one block (128 thr = 2 waves) per row i. Lane owns 4 consecutive
// j via one float4 load per f; Hi/dW2 broadcast from LDS. Cross-wave reduce.
// grid BN = 2048 blocks -> 16 waves/CU.
// ---------------------------------------------------------------------------
__global__ __launch_bounds__(128) void k_score(
    const float* __restrict__ Hi, const float* __restrict__ HjT,
    const float* __restrict__ A, const float* __restrict__ dW2,
    const float* __restrict__ db2,
    float* __restrict__ maxc, float* __restrict__ degv,
    float* __restrict__ maskout) {
    __shared__ float sHi[F_], sW2[F_];
    __shared__ float red_mx[2];
    __shared__ int   red_cnt[2];
    const int t = threadIdx.x;
    const int lane = t & 63;
    const int w = t >> 6;                    // wave id 0/1
    const int bi = blockIdx.x;               // flat row (b*N+i)
    const int b = bi >> 9;

    sHi[t] = Hi[(size_t)bi * F_ + t];
    sW2[t] = dW2[t];
    __syncthreads();

    const int n0 = w * 256 + 4 * lane;       // this thread's 4 j's
    const float* hjp = HjT + (size_t)b * F_ * N_ + n0;

    float4 acc = {0.f, 0.f, 0.f, 0.f};
    #pragma unroll 4
    for (int f = 0; f < F_; ++f) {
        const float4 hj = *reinterpret_cast<const float4*>(hjp + (size_t)f * N_);
        const float hi = sHi[f];
        const float wv = sW2[f];
        acc.x = fmaf(elu_f(hi + hj.x), wv, acc.x);
        acc.y = fmaf(elu_f(hi + hj.y), wv, acc.y);
        acc.z = fmaf(elu_f(hi + hj.z), wv, acc.z);
        acc.w = fmaf(elu_f(hi + hj.w), wv, acc.w);
    }

    const float4 a4 = *reinterpret_cast<const float4*>(A + (size_t)bi * N_ + n0);
    int cnt = (a4.x > 0.f) + (a4.y > 0.f) + (a4.z > 0.f) + (a4.w > 0.f);
    float mx = -INFINITY;
    if (a4.x > 0.1f) mx = fmaxf(mx, acc.x);
    if (a4.y > 0.1f) mx = fmaxf(mx, acc.y);
    if (a4.z > 0.1f) mx = fmaxf(mx, acc.z);
    if (a4.w > 0.1f) mx = fmaxf(mx, acc.w);

    #pragma unroll
    for (int off = 1; off < 64; off <<= 1) {
        mx = fmaxf(mx, __shfl_xor(mx, off));
        cnt += __shfl_xor(cnt, off);
    }
    if (lane == 0) { red_mx[w] = mx; red_cnt[w] = cnt; }
    __syncthreads();
    if (t == 0) {
        const float m = fmaxf(red_mx[0], red_mx[1]);
        const int   c = red_cnt[0] + red_cnt[1];
        const float mc = (m > -INFINITY)
                       ? 1.f / (1.f + __expf(-(m + db2[0]))) : 0.f;
        maxc[bi] = mc;
        degv[bi] = (float)c;
        maskout[bi] = (mc > 0.5f) ? 1.f : 0.f;
    }
}

// ---------------------------------------------------------------------------
// Kernel N: neighbor_feat[bi][f] = sum_{j: A>0} H[b][j][f] / max(deg,1)
// Branchless 0/1 mask in LDS; 2 rows/block, 256 threads (f = t&127, jh=t>>7).
// ---------------------------------------------------------------------------
__global__ __launch_bounds__(256) void k_nbr(
    const float* __restrict__ A, const float* __restrict__ H,
    const float* __restrict__ degv, float* __restrict__ nf) {
    __shared__ float sm[2][N_];
    __shared__ float part[2][F_];
    const int t  = threadIdx.x;
    const int f  = t & 127;
    const int jh = t >> 7;
    const int bi0 = blockIdx.x * 2;
    const int b = bi0 >> 9;

    #pragma unroll
    for (int r = 0; r < 2; ++r)
        for (int j = t; j < N_; j += 256)
            sm[r][j] = (A[(size_t)(bi0 + r) * N_ + j] > 0.f) ? 1.f : 0.f;
    __syncthreads();

    const float* hb = H + ((size_t)b * N_ + jh * 256) * F_ + f;
    const float* m0 = &sm[0][jh * 256];
    const float* m1 = &sm[1][jh * 256];
    float a0 = 0.f, a1 = 0.f;
    #pragma unroll 8
    for (int j = 0; j < 256; ++j) {
        const float h = hb[(size_t)j * F_];
        a0 = fmaf(m0[j], h, a0);
        a1 = fmaf(m1[j], h, a1);
    }
    if (jh == 1) { part[0][f] = a0; part[1][f] = a1; }
    __syncthreads();
    if (jh == 0) {
        const float s0 = a0 + part[0][f];
        const float s1 = a1 + part[1][f];
        nf[(size_t)(bi0 + 0) * F_ + f] = s0 / fmaxf(degv[bi0 + 0], 1.f);
        nf[(size_t)(bi0 + 1) * F_ + f] = s1 / fmaxf(degv[bi0 + 1], 1.f);
    }
}

// ---------------------------------------------------------------------------
// Kernel C: res = elu([H,nf,maxc] @ rW1 + rb1) @ rW2 + rb2; select per row.
// 512 threads = 8 waves: f = t&127, kq = t>>7 owns a K-quarter.
// LDS partial-sum reduce between layers. grid BN/8 = 256 blocks.
// ---------------------------------------------------------------------------
__global__ __launch_bounds__(512) void k_mlp(
    const float* __restrict__ H, const float* __restrict__ nf,
    const float* __restrict__ maxc, const float* __restrict__ degv,
    const float* __restrict__ rW1, const float* __restrict__ rb1,
    const float* __restrict__ rW2, const float* __restrict__ rb2,
    float* __restrict__ out) {
    __shared__ float sC[8][260];             // [r][0..127]=H, [128..255]=nf, [256]=maxc
    __shared__ float sP[3][8][F_];           // partials from kq=1..3
    __shared__ float sL1[8][F_];
    const int t  = threadIdx.x;
    const int f  = t & 127;
    const int kq = t >> 7;                   // 0..3 K-quarter
    const int row0 = blockIdx.x * 8;

    // stage inputs: 8 rows x 128 H + 128 nf
    for (int idx = t; idx < 8 * F_; idx += 512) {
        const int r = idx >> 7, c = idx & 127;
        sC[r][c]        = H [(size_t)(row0 + r) * F_ + c];
        sC[r][F_ + c]   = nf[(size_t)(row0 + r) * F_ + c];
    }
    if (t < 8) sC[t][2 * F_] = maxc[row0 + t];
    __syncthreads();

    // ---- layer 1: [8 x 257] @ [257 x 128], K split across kq ----
    float acc[8];
    #pragma unroll
    for (int r = 0; r < 8; ++r) acc[r] = (kq == 0) ? rb1[f] : 0.f;
    const int k0 = kq * 64;
    const int k1 = (kq == 3) ? 257 : (k0 + 64);
    for (int k = k0; k < k1; ++k) {
        const float wv = rW1[(size_t)k * F_ + f];
        #pragma unroll
        for (int r = 0; r < 8; ++r) acc[r] = fmaf(sC[r][k], wv, acc[r]);
    }
    if (kq > 0) {
        #pragma unroll
        for (int r = 0; r < 8; ++r) sP[kq - 1][r][f] = acc[r];
    }
    __syncthreads();
    if (kq == 0) {
        #pragma unroll
        for (int r = 0; r < 8; ++r) {
            const float v = acc[r] + sP[0][r][f] + sP[1][r][f] + sP[2][r][f];
            sL1[r][f] = elu_f(v);
        }
    }
    __syncthreads();

    // ---- layer 2: [8 x 128] @ [128 x 128], K split across kq ----
    float acc2[8];
    #pragma unroll
    for (int r = 0; r < 8; ++r) acc2[r] = (kq == 0) ? rb2[f] : 0.f;
    const int m0 = kq * 32;
    for (int k = m0; k < m0 + 32; ++k) {
        const float wv = rW2[(size_t)k * F_ + f];
        #pragma unroll
        for (int r = 0; r < 8; ++r) acc2[r] = fmaf(sL1[r][k], wv, acc2[r]);
    }
    if (kq > 0) {
        #pragma unroll
        for (int r = 0; r < 8; ++r) sP[kq - 1][r][f] = acc2[r];
    }
    __syncthreads();
    if (kq == 0) {
        #pragma unroll
        for (int r = 0; r < 8; ++r) {
            const int row = row0 + r;
            const float res = acc2[r] + sP[0][r][f] + sP[1][r][f] + sP[2][r][f];
            const bool upd = (maxc[row] > 0.5f) && (degv[row] > 0.f);
            out[(size_t)row * F_ + f] = upd ? res : sC[r][f];
        }
    }
}

// ---------------------------------------------------------------------------
extern "C" void kernel_launch(void* const* d_in, const int* in_sizes, int n_in,
                              void* d_out, int out_size, void* d_ws, size_t ws_size,
                              hipStream_t stream) {
    const float* H   = (const float*)d_in[0];
    const float* A   = (const float*)d_in[1];
    const float* dW1 = (const float*)d_in[2];
    const float* db1 = (const float*)d_in[3];
    const float* dW2 = (const float*)d_in[4];
    const float* db2 = (const float*)d_in[5];
    const float* rW1 = (const float*)d_in[6];
    const float* rb1 = (const float*)d_in[7];
    const float* rW2 = (const float*)d_in[8];
    const float* rb2 = (const float*)d_in[9];

    float* ws   = (float*)d_ws;
    float* Hi   = ws;                      // [BN][F]
    float* HjT  = Hi + BN_ * F_;           // [B][F][N]
    float* maxc = HjT + BN_ * F_;          // [BN]
    float* degv = maxc + BN_;              // [BN]
    float* nf   = degv + BN_;              // [BN][F]

    float* out      = (float*)d_out;       // [BN][F] H_resolved
    float* mask_out = out + BN_ * F_;      // [BN] contra_mask as 0/1

    k_lin1 <<<BN_ / 8, 128, 0, stream>>>(H, dW1, db1, Hi, HjT);
    k_score<<<BN_,     128, 0, stream>>>(Hi, HjT, A, dW2, db2, maxc, degv, mask_out);
    k_nbr  <<<BN_ / 2, 256, 0, stream>>>(A, H, degv, nf);
    k_mlp  <<<BN_ / 8, 512, 0, stream>>>(H, nf, maxc, degv, rW1, rb1, rW2, rb2, out);
}

// Round 4
// 61.016 us; speedup vs baseline: 4.3059x; 1.1674x over previous
//
#include <hip/hip_runtime.h>
#include <cmath>

#define B_ 4
#define N_ 512
#define F_ 128
#define BN_ (B_*N_)   // 2048

__device__ __forceinline__ float elu_f(float x) {
    return x > 0.f ? x : __expf(x) - 1.f;
}

// ---------------------------------------------------------------------------
// Kernel A: Hi = H @ dW1[:F] + db1 (bias folded), HjT[b][f][n] = (H @ dW1[F:])^T
// 4 rows/block, 256 threads: f = t&127, kh = t>>7 owns a K-half.
// ---------------------------------------------------------------------------
__global__ __launch_bounds__(256) void k_lin1(
    const float* __restrict__ H, const float* __restrict__ dW1,
    const float* __restrict__ db1,
    float* __restrict__ Hi, float* __restrict__ HjT) {
    __shared__ float sH[4][F_];
    __shared__ float sPA[4][F_], sPB[4][F_];
    const int t = threadIdx.x;
    const int f = t & 127;
    const int kh = t >> 7;               // 0/1 K-half
    const int row0 = blockIdx.x * 4;

    #pragma unroll
    for (int p = 0; p < 2; ++p) {
        const int idx = t + p * 256;
        sH[idx >> 7][idx & 127] = H[(size_t)(row0 + (idx >> 7)) * F_ + (idx & 127)];
    }
    __syncthreads();

    float accA[4] = {0.f,0.f,0.f,0.f}, accB[4] = {0.f,0.f,0.f,0.f};
    const int k0 = kh * 64;
    #pragma unroll 4
    for (int k = k0; k < k0 + 64; ++k) {
        const float wa = dW1[(size_t)k * F_ + f];
        const float wb = dW1[(size_t)(F_ + k) * F_ + f];
        #pragma unroll
        for (int r = 0; r < 4; ++r) {
            accA[r] = fmaf(sH[r][k], wa, accA[r]);
            accB[r] = fmaf(sH[r][k], wb, accB[r]);
        }
    }
    if (kh == 1) {
        #pragma unroll
        for (int r = 0; r < 4; ++r) { sPA[r][f] = accA[r]; sPB[r][f] = accB[r]; }
    }
    __syncthreads();
    if (kh == 0) {
        const float bias = db1[f];
        const int b  = row0 >> 9;
        const int n0 = row0 & 511;
        #pragma unroll
        for (int r = 0; r < 4; ++r)
            Hi[(size_t)(row0 + r) * F_ + f] = accA[r] + sPA[r][f] + bias;
        float4 hv;
        hv.x = accB[0] + sPB[0][f];
        hv.y = accB[1] + sPB[1][f];
        hv.z = accB[2] + sPB[2][f];
        hv.w = accB[3] + sPB[3][f];
        *reinterpret_cast<float4*>(HjT + ((size_t)b * F_ + f) * N_ + n0) = hv;
    }
}

// ---------------------------------------------------------------------------
// Kernel B: 4 rows i per block, 512 threads (thread = j). HjT read once per
// block serves 4 rows (L2 traffic /4). A prefetched to regs. Wave reduce,
// then cross-wave via LDS. grid BN/4 = 512 blocks.
// ---------------------------------------------------------------------------
__global__ __launch_bounds__(512) void k_score(
    const float* __restrict__ Hi, const float* __restrict__ HjT,
    const float* __restrict__ A, const float* __restrict__ dW2,
    const float* __restrict__ db2,
    float* __restrict__ maxc, float* __restrict__ degv,
    float* __restrict__ maskout) {
    __shared__ float sHi[4][F_], sW2[F_];
    __shared__ float red_mx[8][4];
    __shared__ int   red_cnt[8][4];
    const int t = threadIdx.x;            // == j
    const int lane = t & 63;
    const int w = t >> 6;                 // wave 0..7
    const int bi0 = blockIdx.x * 4;
    const int b = bi0 >> 9;

    sHi[t >> 7][t & 127] = Hi[(size_t)(bi0 + (t >> 7)) * F_ + (t & 127)];
    if (t < F_) sW2[t] = dW2[t];

    float a_r[4];
    #pragma unroll
    for (int r = 0; r < 4; ++r) a_r[r] = A[(size_t)(bi0 + r) * N_ + t];
    __syncthreads();

    const float* hjp = HjT + (size_t)b * F_ * N_ + t;
    float acc[4] = {0.f,0.f,0.f,0.f};
    #pragma unroll 4
    for (int f = 0; f < F_; ++f) {
        const float hj = hjp[(size_t)f * N_];
        const float wv = sW2[f];
        #pragma unroll
        for (int r = 0; r < 4; ++r)
            acc[r] = fmaf(elu_f(sHi[r][f] + hj), wv, acc[r]);
    }

    #pragma unroll
    for (int r = 0; r < 4; ++r) {
        float mx = (a_r[r] > 0.1f) ? acc[r] : -INFINITY;
        int cnt = (a_r[r] > 0.f) ? 1 : 0;
        #pragma unroll
        for (int off = 1; off < 64; off <<= 1) {
            mx = fmaxf(mx, __shfl_xor(mx, off));
            cnt += __shfl_xor(cnt, off);
        }
        if (lane == 0) { red_mx[w][r] = mx; red_cnt[w][r] = cnt; }
    }
    __syncthreads();
    if (t < 4) {
        float m = -INFINITY; int c = 0;
        #pragma unroll
        for (int ww = 0; ww < 8; ++ww) {
            m = fmaxf(m, red_mx[ww][t]);
            c += red_cnt[ww][t];
        }
        const float mc = (m > -INFINITY)
                       ? 1.f / (1.f + __expf(-(m + db2[0]))) : 0.f;
        maxc[bi0 + t] = mc;
        degv[bi0 + t] = (float)c;
        maskout[bi0 + t] = (mc > 0.5f) ? 1.f : 0.f;
    }
}

// ---------------------------------------------------------------------------
// Kernel N: neighbor mean. 4 rows/block, 512 threads: f = t&127, jq = t>>7
// owns a j-quarter. Branchless mask in LDS; partial-sum reduce via LDS.
// ---------------------------------------------------------------------------
__global__ __launch_bounds__(512) void k_nbr(
    const float* __restrict__ A, const float* __restrict__ H,
    const float* __restrict__ degv, float* __restrict__ nf) {
    __shared__ float sm[4][N_];
    __shared__ float part[3][4][F_];
    const int t  = threadIdx.x;
    const int f  = t & 127;
    const int jq = t >> 7;                // 0..3
    const int bi0 = blockIdx.x * 4;
    const int b = bi0 >> 9;

    #pragma unroll
    for (int r = 0; r < 4; ++r)
        sm[r][t] = (A[(size_t)(bi0 + r) * N_ + t] > 0.f) ? 1.f : 0.f;
    __syncthreads();

    const float* hb = H + ((size_t)b * N_ + jq * 128) * F_ + f;
    const float* m0 = &sm[0][jq * 128];
    const float* m1 = &sm[1][jq * 128];
    const float* m2 = &sm[2][jq * 128];
    const float* m3 = &sm[3][jq * 128];
    float acc[4] = {0.f,0.f,0.f,0.f};
    #pragma unroll 4
    for (int j = 0; j < 128; ++j) {
        const float h = hb[(size_t)j * F_];
        acc[0] = fmaf(m0[j], h, acc[0]);
        acc[1] = fmaf(m1[j], h, acc[1]);
        acc[2] = fmaf(m2[j], h, acc[2]);
        acc[3] = fmaf(m3[j], h, acc[3]);
    }
    if (jq > 0) {
        #pragma unroll
        for (int r = 0; r < 4; ++r) part[jq - 1][r][f] = acc[r];
    }
    __syncthreads();
    if (jq == 0) {
        #pragma unroll
        for (int r = 0; r < 4; ++r) {
            const float s = acc[r] + part[0][r][f] + part[1][r][f] + part[2][r][f];
            nf[(size_t)(bi0 + r) * F_ + f] = s / fmaxf(degv[bi0 + r], 1.f);
        }
    }
}

// ---------------------------------------------------------------------------
// Kernel C: res = elu([H,nf,maxc] @ rW1 + rb1) @ rW2 + rb2; select per row.
// 4 rows/block, 512 blocks, 512 threads: f = t&127, kq = t>>7 K-quarter.
// ---------------------------------------------------------------------------
__global__ __launch_bounds__(512) void k_mlp(
    const float* __restrict__ H, const float* __restrict__ nf,
    const float* __restrict__ maxc, const float* __restrict__ degv,
    const float* __restrict__ rW1, const float* __restrict__ rb1,
    const float* __restrict__ rW2, const float* __restrict__ rb2,
    float* __restrict__ out) {
    __shared__ float sC[4][260];
    __shared__ float sP[3][4][F_];
    __shared__ float sL1[4][F_];
    const int t  = threadIdx.x;
    const int f  = t & 127;
    const int kq = t >> 7;                // 0..3
    const int row0 = blockIdx.x * 4;

    #pragma unroll
    for (int p = 0; p < 2; ++p) {
        const int idx = t + p * 512;      // 0..1023
        const int r = idx >> 8;           // 0..3
        const int c = idx & 255;          // 0..255
        sC[r][c] = (c < F_) ? H [(size_t)(row0 + r) * F_ + c]
                            : nf[(size_t)(row0 + r) * F_ + (c - F_)];
    }
    if (t < 4) sC[t][2 * F_] = maxc[row0 + t];
    __syncthreads();

    // ---- layer 1: [4 x 257] @ [257 x 128], K split across kq ----
    float acc[4];
    #pragma unroll
    for (int r = 0; r < 4; ++r) acc[r] = (kq == 0) ? rb1[f] : 0.f;
    const int k0 = kq * 64;
    const int k1 = (kq == 3) ? 257 : (k0 + 64);
    #pragma unroll 4
    for (int k = k0; k < k1; ++k) {
        const float wv = rW1[(size_t)k * F_ + f];
        #pragma unroll
        for (int r = 0; r < 4; ++r) acc[r] = fmaf(sC[r][k], wv, acc[r]);
    }
    if (kq > 0) {
        #pragma unroll
        for (int r = 0; r < 4; ++r) sP[kq - 1][r][f] = acc[r];
    }
    __syncthreads();
    if (kq == 0) {
        #pragma unroll
        for (int r = 0; r < 4; ++r)
            sL1[r][f] = elu_f(acc[r] + sP[0][r][f] + sP[1][r][f] + sP[2][r][f]);
    }
    __syncthreads();

    // ---- layer 2: [4 x 128] @ [128 x 128], K split across kq ----
    float acc2[4];
    #pragma unroll
    for (int r = 0; r < 4; ++r) acc2[r] = (kq == 0) ? rb2[f] : 0.f;
    const int m0k = kq * 32;
    #pragma unroll 4
    for (int k = m0k; k < m0k + 32; ++k) {
        const float wv = rW2[(size_t)k * F_ + f];
        #pragma unroll
        for (int r = 0; r < 4; ++r) acc2[r] = fmaf(sL1[r][k], wv, acc2[r]);
    }
    if (kq > 0) {
        #pragma unroll
        for (int r = 0; r < 4; ++r) sP[kq - 1][r][f] = acc2[r];
    }
    __syncthreads();
    if (kq == 0) {
        #pragma unroll
        for (int r = 0; r < 4; ++r) {
            const int row = row0 + r;
            const float res = acc2[r] + sP[0][r][f] + sP[1][r][f] + sP[2][r][f];
            const bool upd = (maxc[row] > 0.5f) && (degv[row] > 0.f);
            out[(size_t)row * F_ + f] = upd ? res : sC[r][f];
        }
    }
}

// ---------------------------------------------------------------------------
extern "C" void kernel_launch(void* const* d_in, const int* in_sizes, int n_in,
                              void* d_out, int out_size, void* d_ws, size_t ws_size,
                              hipStream_t stream) {
    const float* H   = (const float*)d_in[0];
    const float* A   = (const float*)d_in[1];
    const float* dW1 = (const float*)d_in[2];
    const float* db1 = (const float*)d_in[3];
    const float* dW2 = (const float*)d_in[4];
    const float* db2 = (const float*)d_in[5];
    const float* rW1 = (const float*)d_in[6];
    const float* rb1 = (const float*)d_in[7];
    const float* rW2 = (const float*)d_in[8];
    const float* rb2 = (const float*)d_in[9];

    float* ws   = (float*)d_ws;
    float* Hi   = ws;                      // [BN][F]
    float* HjT  = Hi + BN_ * F_;           // [B][F][N]
    float* maxc = HjT + BN_ * F_;          // [BN]
    float* degv = maxc + BN_;              // [BN]
    float* nf   = degv + BN_;              // [BN][F]

    float* out      = (float*)d_out;       // [BN][F] H_resolved
    float* mask_out = out + BN_ * F_;      // [BN] contra_mask as 0/1

    k_lin1 <<<BN_ / 4, 256, 0, stream>>>(H, dW1, db1, Hi, HjT);
    k_score<<<BN_ / 4, 512, 0, stream>>>(Hi, HjT, A, dW2, db2, maxc, degv, mask_out);
    k_nbr  <<<BN_ / 4, 512, 0, stream>>>(A, H, degv, nf);
    k_mlp  <<<BN_ / 4, 512, 0, stream>>>(H, nf, maxc, degv, rW1, rb1, rW2, rb2, out);
}